// Round 1
// baseline (320.235 us; speedup 1.0000x reference)
//
#include <hip/hip_runtime.h>

typedef unsigned short u16;
typedef __attribute__((ext_vector_type(8))) short short8;
typedef __attribute__((ext_vector_type(4))) short short4v;
typedef __attribute__((ext_vector_type(4))) float f32x4;
typedef __attribute__((ext_vector_type(4))) unsigned int uint4v;

#define MFMA16(a, b, c) __builtin_amdgcn_mfma_f32_16x16x32_bf16(a, b, c, 0, 0, 0)

#define BB 8
#define NN 1024
#define DD 1024
#define HH 16
#define HD 64
#define MM (BB * NN)

static __device__ __forceinline__ u16 f2bf(float f) {
  unsigned u = __float_as_uint(f);
  u += 0x7fffu + ((u >> 16) & 1u);  // RNE
  return (u16)(u >> 16);
}

static __device__ __forceinline__ void gld16(const void* g, void* l) {
  __builtin_amdgcn_global_load_lds((const __attribute__((address_space(1))) void*)g,
                                   (__attribute__((address_space(3))) void*)l, 16, 0, 0);
}

static __device__ __forceinline__ unsigned cvtpk(float lo, float hi) {
  unsigned r;
  asm("v_cvt_pk_bf16_f32 %0, %1, %2" : "=v"(r) : "v"(lo), "v"(hi));
  return r;
}

// ---------------- lengths from mask (auto-detect bool-byte vs int32) --------
__global__ void lens_kernel(const unsigned char* __restrict__ mask, int* __restrict__ lens) {
  __shared__ int acc[BB];
  const int t = threadIdx.x;
  if (t < BB) acc[t] = 0;
  __syncthreads();
  // lengths >= 512, so element 1 is always true. bool storage: byte1 == 1.
  // int32 storage: byte1 = high byte of element0 == 0. (f32 storage also lands
  // in the "else" branch and the !=0 test on the 4-byte word still works.)
  const bool isbyte = (mask[1] != 0);
  for (int b = 0; b < BB; ++b) {
    int s = 0;
    if (isbyte) {
      for (int i = t; i < NN; i += 256) s += mask[(size_t)b * NN + i] ? 1 : 0;
    } else {
      const int* mi = (const int*)mask;
      for (int i = t; i < NN; i += 256) s += mi[(size_t)b * NN + i] != 0 ? 1 : 0;
    }
    if (s) atomicAdd(&acc[b], s);
  }
  __syncthreads();
  if (t < BB) lens[t] = acc[t];
}

// ---------------- f32 -> bf16 cast (8 elems/thread) -------------------------
__global__ __launch_bounds__(256) void cast_bf16_kernel(const float* __restrict__ in,
                                                        u16* __restrict__ out, int n8) {
  const int i = blockIdx.x * 256 + threadIdx.x;
  if (i >= n8) return;
  const f32x4* p = (const f32x4*)in + (size_t)i * 2;
  const f32x4 a = p[0], b = p[1];
  short8 o;
  o[0] = (short)f2bf(a[0]); o[1] = (short)f2bf(a[1]);
  o[2] = (short)f2bf(a[2]); o[3] = (short)f2bf(a[3]);
  o[4] = (short)f2bf(b[0]); o[5] = (short)f2bf(b[1]);
  o[6] = (short)f2bf(b[2]); o[7] = (short)f2bf(b[3]);
  *(short8*)(out + (size_t)i * 8) = o;
}

// ---------------- GEMM: C = A @ B^T, A[M,1024] bf16, B[1024,1024] bf16 ------
// EPI 0: C bf16 [M,1024] row-major (K,Q)
// EPI 1: C bf16 stored transposed per head: Vt[(b*16+h)*64+x][j]  (V)
// EPI 2: C f32 [M,1024] with +bias and mask-zero rows (final output)
template <int EPI>
__global__ __launch_bounds__(256) void gemm_bt(const u16* __restrict__ A, const u16* __restrict__ Bw,
                                               void* __restrict__ Cout, const float* __restrict__ bias,
                                               const int* __restrict__ lens) {
  constexpr int K = 1024;
  __shared__ u16 As[128 * 32];
  __shared__ u16 Bs[128 * 32];
  const int m0 = blockIdx.x * 128;
  const int n0 = blockIdx.y * 128;
  const int t = threadIdx.x;
  const int lane = t & 63;
  const int w = t >> 6;
  const int wr = w >> 1, wc = w & 1;
  const int li = lane & 15, lg = lane >> 4;
  f32x4 acc[4][4] = {};
  const int off0 = t * 16, off1 = (256 + t) * 16;
  const int r0 = off0 >> 6, kb0 = (off0 & 63) >> 1;
  const int r1 = off1 >> 6, kb1 = (off1 & 63) >> 1;

  for (int k0 = 0; k0 < K; k0 += 32) {
    __syncthreads();  // previous iter's ds_reads done before overwrite
    gld16(A + (size_t)(m0 + r0) * K + k0 + kb0, As + off0 / 2);
    gld16(A + (size_t)(m0 + r1) * K + k0 + kb1, As + off1 / 2);
    gld16(Bw + (size_t)(n0 + r0) * K + k0 + kb0, Bs + off0 / 2);
    gld16(Bw + (size_t)(n0 + r1) * K + k0 + kb1, Bs + off1 / 2);
    __syncthreads();  // compiler drains vmcnt before barrier -> staging visible
    short8 af[4], bf[4];
#pragma unroll
    for (int mi = 0; mi < 4; ++mi)
      af[mi] = *(const short8*)(As + (wr * 64 + mi * 16 + li) * 32 + lg * 8);
#pragma unroll
    for (int ni = 0; ni < 4; ++ni)
      bf[ni] = *(const short8*)(Bs + (wc * 64 + ni * 16 + li) * 32 + lg * 8);
#pragma unroll
    for (int mi = 0; mi < 4; ++mi)
#pragma unroll
      for (int ni = 0; ni < 4; ++ni) acc[mi][ni] = MFMA16(af[mi], bf[ni], acc[mi][ni]);
  }

  if (EPI == 2) {
    float* C = (float*)Cout;
#pragma unroll
    for (int ni = 0; ni < 4; ++ni) {
      const int col = n0 + wc * 64 + ni * 16 + li;
      const float bv = bias[col];
#pragma unroll
      for (int mi = 0; mi < 4; ++mi) {
        const int rowb = m0 + wr * 64 + mi * 16 + lg * 4;
#pragma unroll
        for (int r = 0; r < 4; ++r) {
          const int row = rowb + r;
          const int bb = row >> 10, ii = row & 1023;
          const float v = (ii < lens[bb]) ? (acc[mi][ni][r] + bv) : 0.f;
          C[(size_t)row * 1024 + col] = v;
        }
      }
    }
  } else if (EPI == 1) {
    u16* Vt = (u16*)Cout;
#pragma unroll
    for (int mi = 0; mi < 4; ++mi) {
      const int row = m0 + wr * 64 + mi * 16 + lg * 4;  // (b, j) index
      const int bb = row >> 10, jj = row & 1023;
#pragma unroll
      for (int ni = 0; ni < 4; ++ni) {
        const int col = n0 + wc * 64 + ni * 16 + li;  // (h, x) index
        const int h = col >> 6, x = col & 63;
        short4v st;
#pragma unroll
        for (int r = 0; r < 4; ++r) st[r] = (short)f2bf(acc[mi][ni][r]);
        *(short4v*)(Vt + ((size_t)((bb * HH + h) * HD + x)) * NN + jj) = st;
      }
    }
  } else {
    u16* C = (u16*)Cout;
#pragma unroll
    for (int mi = 0; mi < 4; ++mi)
#pragma unroll
      for (int ni = 0; ni < 4; ++ni) {
        const int col = n0 + wc * 64 + ni * 16 + li;
        const int rowb = m0 + wr * 64 + mi * 16 + lg * 4;
#pragma unroll
        for (int r = 0; r < 4; ++r) C[(size_t)(rowb + r) * 1024 + col] = f2bf(acc[mi][ni][r]);
      }
  }
}

// ---------------- flash attention, 1 wave per (b, h, 16-row i-tile) ---------
// S[i,j] = 0.125 * K_i . Q_j (reference einsum: keys on i, queries on j),
// softmax over j in [0, len_b), out[i,:] = sum_j p_ij V_j.
// Computed as S^T = mfma(Q, K): lane holds S^T[j=lg*4+r (+16)][i=li].
__global__ __launch_bounds__(64) void attn_kernel(const u16* __restrict__ Kb, const u16* __restrict__ Qb,
                                                  const u16* __restrict__ Vtb, u16* __restrict__ attb,
                                                  const int* __restrict__ lens) {
  const int it = blockIdx.x;
  const int h = blockIdx.y;
  const int b = blockIdx.z;
  const int len = lens[b];
  const int i0 = it * 16;
  if (i0 >= len) return;  // fully-masked rows: zeroed in the final GEMM
  const int l = threadIdx.x;
  const int li = l & 15, lg = l >> 4;

  const size_t krow = ((size_t)(b * NN + i0 + li)) * DD + h * HD;
  const short8 kf0 = *(const short8*)(Kb + krow + lg * 8);
  const short8 kf1 = *(const short8*)(Kb + krow + 32 + lg * 8);
  const size_t vbase = ((size_t)(b * HH + h)) * HD * NN;

  float m_run = -INFINITY, l_run = 0.f;
  f32x4 o0 = {0.f, 0.f, 0.f, 0.f}, o1 = o0, o2 = o0, o3 = o0;
  const int srcA = li + ((lg & 1) << 5);
  const int srcB = srcA + 16;
  const bool hi = (l & 32) != 0;

  for (int j0 = 0; j0 < len; j0 += 32) {
    const size_t qrow0 = ((size_t)(b * NN + j0 + li)) * DD + h * HD;
    const size_t qrow1 = qrow0 + (size_t)16 * DD;
    const short8 q00 = *(const short8*)(Qb + qrow0 + lg * 8);
    const short8 q01 = *(const short8*)(Qb + qrow0 + 32 + lg * 8);
    const short8 q10 = *(const short8*)(Qb + qrow1 + lg * 8);
    const short8 q11 = *(const short8*)(Qb + qrow1 + 32 + lg * 8);
    const f32x4 z = {0.f, 0.f, 0.f, 0.f};
    f32x4 s0 = MFMA16(q00, kf0, z);
    s0 = MFMA16(q01, kf1, s0);
    f32x4 s1 = MFMA16(q10, kf0, z);
    s1 = MFMA16(q11, kf1, s1);

    float p0[4], p1[4];
    float pmax = -INFINITY;
    const int jb = j0 + lg * 4;
#pragma unroll
    for (int r = 0; r < 4; ++r) {
      const float va = (jb + r < len) ? s0[r] * 0.125f : -INFINITY;
      const float vb = (jb + 16 + r < len) ? s1[r] * 0.125f : -INFINITY;
      p0[r] = va;
      p1[r] = vb;
      pmax = fmaxf(pmax, fmaxf(va, vb));
    }
    pmax = fmaxf(pmax, __shfl_xor(pmax, 16));
    pmax = fmaxf(pmax, __shfl_xor(pmax, 32));
    const float m_new = fmaxf(m_run, pmax);
    const float alpha = __expf(m_run - m_new);
    float rs = 0.f;
#pragma unroll
    for (int r = 0; r < 4; ++r) {
      p0[r] = __expf(p0[r] - m_new);
      rs += p0[r];
      p1[r] = __expf(p1[r] - m_new);
      rs += p1[r];
    }
    rs += __shfl_xor(rs, 16);
    rs += __shfl_xor(rs, 32);
    l_run = l_run * alpha + rs;
    m_run = m_new;
    o0 *= alpha; o1 *= alpha; o2 *= alpha; o3 *= alpha;

    // P -> bf16 pairs, relayout (S^T D-layout -> PV B-layout) via 8 shuffles
    const unsigned p00 = cvtpk(p0[0], p0[1]);
    const unsigned p01 = cvtpk(p0[2], p0[3]);
    const unsigned p10 = cvtpk(p1[0], p1[1]);
    const unsigned p11 = cvtpk(p1[2], p1[3]);
    const unsigned a0 = __shfl(p00, srcA), a1 = __shfl(p01, srcA);
    const unsigned a2 = __shfl(p00, srcB), a3 = __shfl(p01, srcB);
    const unsigned b0 = __shfl(p10, srcA), b1 = __shfl(p11, srcA);
    const unsigned b2 = __shfl(p10, srcB), b3 = __shfl(p11, srcB);
    uint4v pw;
    pw[0] = hi ? b0 : a0;
    pw[1] = hi ? b1 : a1;
    pw[2] = hi ? b2 : a2;
    pw[3] = hi ? b3 : a3;
    union { uint4v u; short8 s; } pu;
    pu.u = pw;
    const short8 pf = pu.s;

    const short8 v0 = *(const short8*)(Vtb + vbase + (size_t)(0 + li) * NN + j0 + lg * 8);
    const short8 v1 = *(const short8*)(Vtb + vbase + (size_t)(16 + li) * NN + j0 + lg * 8);
    const short8 v2 = *(const short8*)(Vtb + vbase + (size_t)(32 + li) * NN + j0 + lg * 8);
    const short8 v3 = *(const short8*)(Vtb + vbase + (size_t)(48 + li) * NN + j0 + lg * 8);
    o0 = MFMA16(v0, pf, o0);
    o1 = MFMA16(v1, pf, o1);
    o2 = MFMA16(v2, pf, o2);
    o3 = MFMA16(v3, pf, o3);
  }

  const float inv = 1.f / l_run;
  const size_t arow = ((size_t)(b * NN + i0 + li)) * DD + h * HD;
#define STORE_O(ov, xoff)                                             \
  {                                                                   \
    short4v st;                                                       \
    st[0] = (short)f2bf(ov[0] * inv);                                 \
    st[1] = (short)f2bf(ov[1] * inv);                                 \
    st[2] = (short)f2bf(ov[2] * inv);                                 \
    st[3] = (short)f2bf(ov[3] * inv);                                 \
    *(short4v*)(attb + arow + (xoff) + lg * 4) = st;                  \
  }
  STORE_O(o0, 0)
  STORE_O(o1, 16)
  STORE_O(o2, 32)
  STORE_O(o3, 48)
#undef STORE_O
}

// ---------------------------------------------------------------------------
extern "C" void kernel_launch(void* const* d_in, const int* in_sizes, int n_in,
                              void* d_out, int out_size, void* d_ws, size_t ws_size,
                              hipStream_t stream) {
  const float* x = (const float*)d_in[0];
  const unsigned char* mask = (const unsigned char*)d_in[1];
  const float* Wk = (const float*)d_in[2];
  const float* Wq = (const float*)d_in[3];
  const float* Wv = (const float*)d_in[4];
  const float* Wo = (const float*)d_in[5];
  const float* bo = (const float*)d_in[6];
  float* out = (float*)d_out;

  char* ws = (char*)d_ws;
  size_t o = 0;
  int* lens = (int*)(ws + o); o += 256;
  u16* xb  = (u16*)(ws + o); o += (size_t)MM * DD * 2;   // 16.78 MB
  u16* wkb = (u16*)(ws + o); o += (size_t)DD * DD * 2;   // 2.1 MB
  u16* wqb = (u16*)(ws + o); o += (size_t)DD * DD * 2;
  u16* wvb = (u16*)(ws + o); o += (size_t)DD * DD * 2;
  u16* wob = (u16*)(ws + o); o += (size_t)DD * DD * 2;
  u16* kb  = (u16*)(ws + o); o += (size_t)MM * DD * 2;
  u16* qb  = (u16*)(ws + o); o += (size_t)MM * DD * 2;
  u16* vtb = (u16*)(ws + o); o += (size_t)MM * DD * 2;
  u16* attb = xb;  // alias: x only needed until projections finish

  lens_kernel<<<dim3(1), dim3(256), 0, stream>>>(mask, lens);

  const int xn8 = MM * DD / 8;   // 1048576
  const int wn8 = DD * DD / 8;   // 131072
  cast_bf16_kernel<<<dim3(xn8 / 256), dim3(256), 0, stream>>>(x, xb, xn8);
  cast_bf16_kernel<<<dim3(wn8 / 256), dim3(256), 0, stream>>>(Wk, wkb, wn8);
  cast_bf16_kernel<<<dim3(wn8 / 256), dim3(256), 0, stream>>>(Wq, wqb, wn8);
  cast_bf16_kernel<<<dim3(wn8 / 256), dim3(256), 0, stream>>>(Wv, wvb, wn8);
  cast_bf16_kernel<<<dim3(wn8 / 256), dim3(256), 0, stream>>>(Wo, wob, wn8);

  const dim3 ggrid(MM / 128, DD / 128);  // 64 x 8
  gemm_bt<0><<<ggrid, dim3(256), 0, stream>>>(xb, wkb, kb, nullptr, nullptr);
  gemm_bt<0><<<ggrid, dim3(256), 0, stream>>>(xb, wqb, qb, nullptr, nullptr);
  gemm_bt<1><<<ggrid, dim3(256), 0, stream>>>(xb, wvb, vtb, nullptr, nullptr);

  attn_kernel<<<dim3(NN / 16, HH, BB), dim3(64), 0, stream>>>(kb, qb, vtb, attb, lens);

  gemm_bt<2><<<ggrid, dim3(256), 0, stream>>>(attb, wob, out, bo, lens);
}

// Round 3
// 203.460 us; speedup vs baseline: 1.5739x; 1.5739x over previous
//
#include <hip/hip_runtime.h>

typedef unsigned short u16;
typedef __attribute__((ext_vector_type(8))) short short8;
typedef __attribute__((ext_vector_type(4))) short short4v;
typedef __attribute__((ext_vector_type(4))) float f32x4;
typedef __attribute__((ext_vector_type(16))) float f32x16;

#define MFMA16(a, b, c) __builtin_amdgcn_mfma_f32_16x16x32_bf16(a, b, c, 0, 0, 0)
#define MFMA32(a, b, c) __builtin_amdgcn_mfma_f32_32x32x16_bf16(a, b, c, 0, 0, 0)

#define BB 8
#define NN 1024
#define DD 1024
#define HH 16
#define HD 64
#define MM (BB * NN)
// 0.125 (hd^-0.5) * log2(e): softmax computed in exp2 domain
#define SCLOG2 0.18033688011112042f

static __device__ __forceinline__ u16 f2bf(float f) {
  unsigned u = __float_as_uint(f);
  u += 0x7fffu + ((u >> 16) & 1u);  // RNE
  return (u16)(u >> 16);
}

static __device__ __forceinline__ void gld16(const void* g, void* l) {
  __builtin_amdgcn_global_load_lds((const __attribute__((address_space(1))) void*)g,
                                   (__attribute__((address_space(3))) void*)l, 16, 0, 0);
}

static __device__ __forceinline__ unsigned cvtpk(float lo, float hi) {
  unsigned r;
  asm("v_cvt_pk_bf16_f32 %0, %1, %2" : "=v"(r) : "v"(lo), "v"(hi));
  return r;
}

static __device__ __forceinline__ f32x16 zero16() {
  f32x16 v;
#pragma unroll
  for (int i = 0; i < 16; ++i) v[i] = 0.f;
  return v;
}

// ---------------- lengths from mask (auto-detect bool-byte vs int32) --------
__global__ void lens_kernel(const unsigned char* __restrict__ mask, int* __restrict__ lens) {
  __shared__ int acc[BB];
  const int t = threadIdx.x;
  if (t < BB) acc[t] = 0;
  __syncthreads();
  const bool isbyte = (mask[1] != 0);  // lengths >= 512 so element 1 is true
  for (int b = 0; b < BB; ++b) {
    int s = 0;
    if (isbyte) {
      for (int i = t; i < NN; i += 256) s += mask[(size_t)b * NN + i] ? 1 : 0;
    } else {
      const int* mi = (const int*)mask;
      for (int i = t; i < NN; i += 256) s += mi[(size_t)b * NN + i] != 0 ? 1 : 0;
    }
    if (s) atomicAdd(&acc[b], s);
  }
  __syncthreads();
  if (t < BB) lens[t] = acc[t];
}

// ---------------- f32 -> bf16 cast (8 elems/thread) -------------------------
__global__ __launch_bounds__(256) void cast_bf16_kernel(const float* __restrict__ in,
                                                        u16* __restrict__ out, int n8) {
  const int i = blockIdx.x * 256 + threadIdx.x;
  if (i >= n8) return;
  const f32x4* p = (const f32x4*)in + (size_t)i * 2;
  const f32x4 a = p[0], b = p[1];
  short8 o;
  o[0] = (short)f2bf(a[0]); o[1] = (short)f2bf(a[1]);
  o[2] = (short)f2bf(a[2]); o[3] = (short)f2bf(a[3]);
  o[4] = (short)f2bf(b[0]); o[5] = (short)f2bf(b[1]);
  o[6] = (short)f2bf(b[2]); o[7] = (short)f2bf(b[3]);
  *(short8*)(out + (size_t)i * 8) = o;
}

// ---------------- fused cast of the 4 weight matrices -----------------------
__global__ __launch_bounds__(256) void cast4_bf16_kernel(const float* __restrict__ a, const float* __restrict__ b,
                                                         const float* __restrict__ c, const float* __restrict__ d,
                                                         u16* __restrict__ oa, u16* __restrict__ ob,
                                                         u16* __restrict__ oc, u16* __restrict__ od) {
  const int i = blockIdx.x * 256 + threadIdx.x;
  const float* in;
  u16* out;
  switch (blockIdx.y) {
    case 0: in = a; out = oa; break;
    case 1: in = b; out = ob; break;
    case 2: in = c; out = oc; break;
    default: in = d; out = od; break;
  }
  const f32x4* p = (const f32x4*)in + (size_t)i * 2;
  const f32x4 va = p[0], vb = p[1];
  short8 o;
  o[0] = (short)f2bf(va[0]); o[1] = (short)f2bf(va[1]);
  o[2] = (short)f2bf(va[2]); o[3] = (short)f2bf(va[3]);
  o[4] = (short)f2bf(vb[0]); o[5] = (short)f2bf(vb[1]);
  o[6] = (short)f2bf(vb[2]); o[7] = (short)f2bf(vb[3]);
  *(short8*)(out + (size_t)i * 8) = o;
}

// ---------------- GEMM: C = A @ B^T, A[M,1024] bf16, B[1024,1024] bf16 ------
// EPI 0: C bf16 [M,1024] row-major, scaled (K,Q)
// EPI 1: C bf16 stored transposed per head: Vt[(b*16+h)*64+x][j]  (V)
// EPI 2: C f32 [M,1024] with +bias and mask-zero rows (final output)
template <int EPI>
__global__ __launch_bounds__(256) void gemm_bt(const u16* __restrict__ A, const u16* __restrict__ Bw,
                                               void* __restrict__ Cout, const float* __restrict__ bias,
                                               const int* __restrict__ lens, float scale) {
  constexpr int K = 1024;
  __shared__ u16 As[128 * 32];
  __shared__ u16 Bs[128 * 32];
  const int m0 = blockIdx.x * 128;
  const int n0 = blockIdx.y * 128;
  const int t = threadIdx.x;
  const int lane = t & 63;
  const int w = t >> 6;
  const int wr = w >> 1, wc = w & 1;
  const int li = lane & 15, lg = lane >> 4;
  f32x4 acc[4][4] = {};
  const int off0 = t * 16, off1 = (256 + t) * 16;
  const int r0 = off0 >> 6, kb0 = (off0 & 63) >> 1;
  const int r1 = off1 >> 6, kb1 = (off1 & 63) >> 1;

  for (int k0 = 0; k0 < K; k0 += 32) {
    __syncthreads();
    gld16(A + (size_t)(m0 + r0) * K + k0 + kb0, As + off0 / 2);
    gld16(A + (size_t)(m0 + r1) * K + k0 + kb1, As + off1 / 2);
    gld16(Bw + (size_t)(n0 + r0) * K + k0 + kb0, Bs + off0 / 2);
    gld16(Bw + (size_t)(n0 + r1) * K + k0 + kb1, Bs + off1 / 2);
    __syncthreads();
    short8 af[4], bf[4];
#pragma unroll
    for (int mi = 0; mi < 4; ++mi)
      af[mi] = *(const short8*)(As + (wr * 64 + mi * 16 + li) * 32 + lg * 8);
#pragma unroll
    for (int ni = 0; ni < 4; ++ni)
      bf[ni] = *(const short8*)(Bs + (wc * 64 + ni * 16 + li) * 32 + lg * 8);
#pragma unroll
    for (int mi = 0; mi < 4; ++mi)
#pragma unroll
      for (int ni = 0; ni < 4; ++ni) acc[mi][ni] = MFMA16(af[mi], bf[ni], acc[mi][ni]);
  }

  if (EPI == 2) {
    float* C = (float*)Cout;
#pragma unroll
    for (int ni = 0; ni < 4; ++ni) {
      const int col = n0 + wc * 64 + ni * 16 + li;
      const float bv = bias[col];
#pragma unroll
      for (int mi = 0; mi < 4; ++mi) {
        const int rowb = m0 + wr * 64 + mi * 16 + lg * 4;
#pragma unroll
        for (int r = 0; r < 4; ++r) {
          const int row = rowb + r;
          const int bb = row >> 10, ii = row & 1023;
          const float v = (ii < lens[bb]) ? (acc[mi][ni][r] + bv) : 0.f;
          C[(size_t)row * 1024 + col] = v;
        }
      }
    }
  } else if (EPI == 1) {
    u16* Vt = (u16*)Cout;
#pragma unroll
    for (int mi = 0; mi < 4; ++mi) {
      const int row = m0 + wr * 64 + mi * 16 + lg * 4;  // (b, j) index
      const int bb = row >> 10, jj = row & 1023;
#pragma unroll
      for (int ni = 0; ni < 4; ++ni) {
        const int col = n0 + wc * 64 + ni * 16 + li;  // (h, x) index
        const int h = col >> 6, x = col & 63;
        short4v st;
#pragma unroll
        for (int r = 0; r < 4; ++r) st[r] = (short)f2bf(acc[mi][ni][r]);
        *(short4v*)(Vt + ((size_t)((bb * HH + h) * HD + x)) * NN + jj) = st;
      }
    }
  } else {
    u16* C = (u16*)Cout;
#pragma unroll
    for (int mi = 0; mi < 4; ++mi)
#pragma unroll
      for (int ni = 0; ni < 4; ++ni) {
        const int col = n0 + wc * 64 + ni * 16 + li;
        const int rowb = m0 + wr * 64 + mi * 16 + lg * 4;
#pragma unroll
        for (int r = 0; r < 4; ++r)
          C[(size_t)(rowb + r) * 1024 + col] = f2bf(acc[mi][ni][r] * scale);
      }
  }
}

// ---------------- flash attention, 4 waves/block, 32 i-rows/wave ------------
// S^T = mfma32(A=Q-frag, B=K-frag): lane l holds col i = l&31,
// row j = (reg&3) + 8*(reg>>2) + 4*(l>>5). Scores already in log2 domain
// (K pre-scaled by 0.125*log2e). Q/V tiles (64 j) double-buffered in LDS in
// FRAGMENT-MAJOR order: 16B unit u = (frag_idx*64 + lane), so ds_read_b128 is
// stride-1 per lane (conflict-free) and global_load_lds dest is linear.
__global__ __launch_bounds__(256) void attn_kernel(const u16* __restrict__ Kb, const u16* __restrict__ Qb,
                                                   const u16* __restrict__ Vtb, u16* __restrict__ attb,
                                                   const int* __restrict__ lens) {
  const int ic = blockIdx.x, h = blockIdx.y, b = blockIdx.z;
  const int len = lens[b];
  const int i0 = ic * 128;
  if (i0 >= len) return;  // fully-masked rows zeroed by final GEMM
  const int t = threadIdx.x;
  const int w = t >> 6, l = t & 63;
  const int l31 = l & 31, hi = l >> 5;
  const int i0w = i0 + w * 32;

  __shared__ u16 Qs[2][4096];  // 8KB per buffer
  __shared__ u16 Vs[2][4096];

  // K fragments (B operand): col i = l31, k(hd) = ks*16 + hi*8 + e
  short8 kf[4];
  {
    const u16* kp = Kb + ((size_t)(b * NN + i0w + l31)) * DD + h * HD + hi * 8;
#pragma unroll
    for (int ks = 0; ks < 4; ++ks) kf[ks] = *(const short8*)(kp + ks * 16);
  }

  // staging sources: thread t fills 16B units u=t and u=t+256 of each tile.
  // Q: u -> (jsub=u>>8, ks=(u>>6)&3, lane=u&63): row j0+jsub*32+l31, hd col ks*16+hi*8
  // V: u -> (xsub, kk, lane): row x=xsub*32+l31, j col j0+kk*16+hi*8
  const size_t qsrc = ((size_t)(b * NN) + l31) * DD + h * HD + w * 16 + hi * 8;
  const size_t vsrc = ((size_t)((b * HH + h) * HD + l31)) * NN + w * 16 + hi * 8;

  auto STAGE = [&](int buf, int j0) {
    u16* qd = &Qs[buf][0] + t * 8;
    u16* vd = &Vs[buf][0] + t * 8;
    gld16(Qb + qsrc + (size_t)j0 * DD, qd);
    gld16(Qb + qsrc + (size_t)(j0 + 32) * DD, qd + 2048);
    gld16(Vtb + vsrc + j0, vd);
    gld16(Vtb + vsrc + 32 * NN + j0, vd + 2048);
  };

  f32x16 o0 = zero16(), o1 = zero16();
  float m_run = -3.0e38f, l_run = 0.f;
  const int nt = (len + 63) >> 6;

  STAGE(0, 0);
  __syncthreads();
  for (int jt = 0; jt < nt; ++jt) {
    const int cur = jt & 1;
    const int j0 = jt * 64;
    if (jt + 1 < nt) STAGE(cur ^ 1, j0 + 64);  // async prefetch, drained at end barrier

    const u16* Qc = &Qs[cur][0];
    const u16* Vc = &Vs[cur][0];
    f32x16 s0 = zero16(), s1 = zero16();
#pragma unroll
    for (int ks = 0; ks < 4; ++ks) {
      const short8 qf = *(const short8*)(Qc + (ks * 64 + l) * 8);
      s0 = MFMA32(qf, kf[ks], s0);
    }
#pragma unroll
    for (int ks = 0; ks < 4; ++ks) {
      const short8 qf = *(const short8*)(Qc + ((4 + ks) * 64 + l) * 8);
      s1 = MFMA32(qf, kf[ks], s1);
    }

    if (j0 + 64 > len) {  // uniform; only possible on last tile
#pragma unroll
      for (int r = 0; r < 16; ++r) {
        const int jl = (r & 3) + 8 * (r >> 2) + 4 * hi;
        if (j0 + jl >= len) s0[r] = -3.0e38f;
        if (j0 + 32 + jl >= len) s1[r] = -3.0e38f;
      }
    }

    float pmax = s0[0];
#pragma unroll
    for (int r = 1; r < 16; ++r) pmax = fmaxf(pmax, s0[r]);
#pragma unroll
    for (int r = 0; r < 16; ++r) pmax = fmaxf(pmax, s1[r]);
    pmax = fmaxf(pmax, __shfl_xor(pmax, 32));

    // defer-max (T13): skip O-rescale while tile max within 11.5 (log2) of m_run
    if (!__all(pmax <= m_run + 11.5f)) {
      const float mnew = fmaxf(m_run, pmax);
      const float al = __builtin_amdgcn_exp2f(m_run - mnew);
      l_run *= al;
#pragma unroll
      for (int r = 0; r < 16; ++r) { o0[r] *= al; o1[r] *= al; }
      m_run = mnew;
    }

    float rs = 0.f;
#pragma unroll
    for (int r = 0; r < 16; ++r) { const float p = __builtin_amdgcn_exp2f(s0[r] - m_run); s0[r] = p; rs += p; }
#pragma unroll
    for (int r = 0; r < 16; ++r) { const float p = __builtin_amdgcn_exp2f(s1[r] - m_run); s1[r] = p; rs += p; }
    rs += __shfl_xor(rs, 32);
    l_run += rs;

    // P -> PV B-fragments: per 16-j chunk, 4 cvt_pk + 2 permlane32_swap (T12).
    // v_permlane32_swap_b32 vdst, vsrc: vdst_new = {vdst.lo, vsrc.lo},
    // vsrc_new = {vdst.hi, vsrc.hi}  (dst HIGH half <-> src LOW half).
    // vdst must be the low-j word (W0/W1), vsrc the +8 word (W2/W3).
    short8 pf[4];
#pragma unroll
    for (int jk = 0; jk < 4; ++jk) {
      const f32x16& ss = (jk < 2) ? s0 : s1;
      const int kk = jk & 1;
      unsigned W0 = cvtpk(ss[8 * kk + 0], ss[8 * kk + 1]);
      unsigned W1 = cvtpk(ss[8 * kk + 2], ss[8 * kk + 3]);
      unsigned W2 = cvtpk(ss[8 * kk + 4], ss[8 * kk + 5]);
      unsigned W3 = cvtpk(ss[8 * kk + 6], ss[8 * kk + 7]);
      asm("v_permlane32_swap_b32 %0, %1" : "+v"(W0), "+v"(W2));
      asm("v_permlane32_swap_b32 %0, %1" : "+v"(W1), "+v"(W3));
      union { unsigned u[4]; short8 s; } pu;
      pu.u[0] = W0; pu.u[1] = W1; pu.u[2] = W2; pu.u[3] = W3;
      pf[jk] = pu.s;
    }

#pragma unroll
    for (int kkg = 0; kkg < 4; ++kkg) {
      const short8 vf = *(const short8*)(Vc + (kkg * 64 + l) * 8);
      o0 = MFMA32(vf, pf[kkg], o0);
    }
#pragma unroll
    for (int kkg = 0; kkg < 4; ++kkg) {
      const short8 vf = *(const short8*)(Vc + ((4 + kkg) * 64 + l) * 8);
      o1 = MFMA32(vf, pf[kkg], o1);
    }
    __syncthreads();  // drains prefetch (vmcnt) + this tile's ds_reads (lgkm)
  }

  const float inv = 1.f / l_run;
  u16* op = attb + (size_t)(b * NN + i0w + l31) * DD + h * HD + hi * 4;
#pragma unroll
  for (int xs = 0; xs < 2; ++xs) {
    const f32x16& oo = xs ? o1 : o0;
#pragma unroll
    for (int q = 0; q < 4; ++q) {
      short4v st;
#pragma unroll
      for (int e = 0; e < 4; ++e) st[e] = (short)f2bf(oo[q * 4 + e] * inv);
      *(short4v*)(op + xs * 32 + q * 8) = st;
    }
  }
}

// ---------------------------------------------------------------------------
extern "C" void kernel_launch(void* const* d_in, const int* in_sizes, int n_in,
                              void* d_out, int out_size, void* d_ws, size_t ws_size,
                              hipStream_t stream) {
  const float* x = (const float*)d_in[0];
  const unsigned char* mask = (const unsigned char*)d_in[1];
  const float* Wk = (const float*)d_in[2];
  const float* Wq = (const float*)d_in[3];
  const float* Wv = (const float*)d_in[4];
  const float* Wo = (const float*)d_in[5];
  const float* bo = (const float*)d_in[6];
  float* out = (float*)d_out;

  char* ws = (char*)d_ws;
  size_t o = 0;
  int* lens = (int*)(ws + o); o += 256;
  u16* xb  = (u16*)(ws + o); o += (size_t)MM * DD * 2;
  u16* wkb = (u16*)(ws + o); o += (size_t)DD * DD * 2;
  u16* wqb = (u16*)(ws + o); o += (size_t)DD * DD * 2;
  u16* wvb = (u16*)(ws + o); o += (size_t)DD * DD * 2;
  u16* wob = (u16*)(ws + o); o += (size_t)DD * DD * 2;
  u16* kb  = (u16*)(ws + o); o += (size_t)MM * DD * 2;
  u16* qb  = (u16*)(ws + o); o += (size_t)MM * DD * 2;
  u16* vtb = (u16*)(ws + o); o += (size_t)MM * DD * 2;
  u16* attb = xb;  // alias: x only needed until projections finish

  lens_kernel<<<dim3(1), dim3(256), 0, stream>>>(mask, lens);

  const int xn8 = MM * DD / 8;
  cast_bf16_kernel<<<dim3(xn8 / 256), dim3(256), 0, stream>>>(x, xb, xn8);
  cast4_bf16_kernel<<<dim3(DD * DD / 8 / 256, 4), dim3(256), 0, stream>>>(
      Wk, Wq, Wv, Wo, wkb, wqb, wvb, wob);

  const dim3 ggrid(MM / 128, DD / 128);  // 64 x 8
  gemm_bt<0><<<ggrid, dim3(256), 0, stream>>>(xb, wkb, kb, nullptr, nullptr, SCLOG2);
  gemm_bt<0><<<ggrid, dim3(256), 0, stream>>>(xb, wqb, qb, nullptr, nullptr, 1.0f);
  gemm_bt<1><<<ggrid, dim3(256), 0, stream>>>(xb, wvb, vtb, nullptr, nullptr, 1.0f);

  attn_kernel<<<dim3(NN / 128, HH, BB), dim3(256), 0, stream>>>(kb, qb, vtb, attb, lens);

  gemm_bt<2><<<ggrid, dim3(256), 0, stream>>>(attb, wob, out, bo, lens, 1.0f);
}

// Round 4
// 200.274 us; speedup vs baseline: 1.5990x; 1.0159x over previous
//
#include <hip/hip_runtime.h>

typedef unsigned short u16;
typedef __attribute__((ext_vector_type(8))) short short8;
typedef __attribute__((ext_vector_type(4))) short short4v;
typedef __attribute__((ext_vector_type(4))) float f32x4;
typedef __attribute__((ext_vector_type(16))) float f32x16;

#define MFMA16(a, b, c) __builtin_amdgcn_mfma_f32_16x16x32_bf16(a, b, c, 0, 0, 0)
#define MFMA32(a, b, c) __builtin_amdgcn_mfma_f32_32x32x16_bf16(a, b, c, 0, 0, 0)

#define BB 8
#define NN 1024
#define DD 1024
#define HH 16
#define HD 64
#define MM (BB * NN)
// 0.125 (hd^-0.5) * log2(e): softmax computed in exp2 domain
#define SCLOG2 0.18033688011112042f

static __device__ __forceinline__ u16 f2bf(float f) {
  unsigned u = __float_as_uint(f);
  u += 0x7fffu + ((u >> 16) & 1u);  // RNE
  return (u16)(u >> 16);
}

static __device__ __forceinline__ void gld16(const void* g, void* l) {
  __builtin_amdgcn_global_load_lds((const __attribute__((address_space(1))) void*)g,
                                   (__attribute__((address_space(3))) void*)l, 16, 0, 0);
}

static __device__ __forceinline__ unsigned cvtpk(float lo, float hi) {
  unsigned r;
  asm("v_cvt_pk_bf16_f32 %0, %1, %2" : "=v"(r) : "v"(lo), "v"(hi));
  return r;
}

static __device__ __forceinline__ f32x16 zero16() {
  f32x16 v;
#pragma unroll
  for (int i = 0; i < 16; ++i) v[i] = 0.f;
  return v;
}

// ---------------- lengths from mask (auto-detect bool-byte vs int32) --------
__global__ void lens_kernel(const unsigned char* __restrict__ mask, int* __restrict__ lens) {
  __shared__ int acc[BB];
  const int t = threadIdx.x;
  if (t < BB) acc[t] = 0;
  __syncthreads();
  const bool isbyte = (mask[1] != 0);  // lengths >= 512 so element 1 is true
  for (int b = 0; b < BB; ++b) {
    int s = 0;
    if (isbyte) {
      for (int i = t; i < NN; i += 256) s += mask[(size_t)b * NN + i] ? 1 : 0;
    } else {
      const int* mi = (const int*)mask;
      for (int i = t; i < NN; i += 256) s += mi[(size_t)b * NN + i] != 0 ? 1 : 0;
    }
    if (s) atomicAdd(&acc[b], s);
  }
  __syncthreads();
  if (t < BB) lens[t] = acc[t];
}

// ---------------- f32 -> bf16 cast (8 elems/thread) -------------------------
__global__ __launch_bounds__(256) void cast_bf16_kernel(const float* __restrict__ in,
                                                        u16* __restrict__ out, int n8) {
  const int i = blockIdx.x * 256 + threadIdx.x;
  if (i >= n8) return;
  const f32x4* p = (const f32x4*)in + (size_t)i * 2;
  const f32x4 a = p[0], b = p[1];
  short8 o;
  o[0] = (short)f2bf(a[0]); o[1] = (short)f2bf(a[1]);
  o[2] = (short)f2bf(a[2]); o[3] = (short)f2bf(a[3]);
  o[4] = (short)f2bf(b[0]); o[5] = (short)f2bf(b[1]);
  o[6] = (short)f2bf(b[2]); o[7] = (short)f2bf(b[3]);
  *(short8*)(out + (size_t)i * 8) = o;
}

// ---------------- fused cast of the 4 weight matrices -----------------------
__global__ __launch_bounds__(256) void cast4_bf16_kernel(const float* __restrict__ a, const float* __restrict__ b,
                                                         const float* __restrict__ c, const float* __restrict__ d,
                                                         u16* __restrict__ oa, u16* __restrict__ ob,
                                                         u16* __restrict__ oc, u16* __restrict__ od) {
  const int i = blockIdx.x * 256 + threadIdx.x;
  const float* in;
  u16* out;
  switch (blockIdx.y) {
    case 0: in = a; out = oa; break;
    case 1: in = b; out = ob; break;
    case 2: in = c; out = oc; break;
    default: in = d; out = od; break;
  }
  const f32x4* p = (const f32x4*)in + (size_t)i * 2;
  const f32x4 va = p[0], vb = p[1];
  short8 o;
  o[0] = (short)f2bf(va[0]); o[1] = (short)f2bf(va[1]);
  o[2] = (short)f2bf(va[2]); o[3] = (short)f2bf(va[3]);
  o[4] = (short)f2bf(vb[0]); o[5] = (short)f2bf(vb[1]);
  o[6] = (short)f2bf(vb[2]); o[7] = (short)f2bf(vb[3]);
  *(short8*)(out + (size_t)i * 8) = o;
}

// ---------------- fused QKV projection: C_m = xb @ W_m^T, m in {k,q,v} ------
// grid (MM/128, 24): blockIdx.y -> (mat = y>>3, n0 = (y&7)*128).
// mat 0 -> kb bf16 row-major scaled by SCLOG2; mat 1 -> qb bf16 row-major;
// mat 2 -> vtb bf16 transposed per head Vt[(b*16+h)*64+x][j].
__global__ __launch_bounds__(256) void gemm_qkv(const u16* __restrict__ A,
                                                const u16* __restrict__ Wk3, const u16* __restrict__ Wq3,
                                                const u16* __restrict__ Wv3,
                                                u16* __restrict__ kb, u16* __restrict__ qb,
                                                u16* __restrict__ vtb) {
  constexpr int K = 1024;
  __shared__ u16 As[128 * 32];
  __shared__ u16 Bs[128 * 32];
  const int m0 = blockIdx.x * 128;
  const int mat = blockIdx.y >> 3;
  const int n0 = (blockIdx.y & 7) * 128;
  const u16* Bw = (mat == 0) ? Wk3 : (mat == 1) ? Wq3 : Wv3;
  const int t = threadIdx.x;
  const int lane = t & 63;
  const int w = t >> 6;
  const int wr = w >> 1, wc = w & 1;
  const int li = lane & 15, lg = lane >> 4;
  f32x4 acc[4][4] = {};
  const int off0 = t * 16, off1 = (256 + t) * 16;
  const int r0 = off0 >> 6, kb0 = (off0 & 63) >> 1;
  const int r1 = off1 >> 6, kb1 = (off1 & 63) >> 1;

  for (int k0 = 0; k0 < K; k0 += 32) {
    __syncthreads();
    gld16(A + (size_t)(m0 + r0) * K + k0 + kb0, As + off0 / 2);
    gld16(A + (size_t)(m0 + r1) * K + k0 + kb1, As + off1 / 2);
    gld16(Bw + (size_t)(n0 + r0) * K + k0 + kb0, Bs + off0 / 2);
    gld16(Bw + (size_t)(n0 + r1) * K + k0 + kb1, Bs + off1 / 2);
    __syncthreads();
    short8 af[4], bf[4];
#pragma unroll
    for (int mi = 0; mi < 4; ++mi)
      af[mi] = *(const short8*)(As + (wr * 64 + mi * 16 + li) * 32 + lg * 8);
#pragma unroll
    for (int ni = 0; ni < 4; ++ni)
      bf[ni] = *(const short8*)(Bs + (wc * 64 + ni * 16 + li) * 32 + lg * 8);
#pragma unroll
    for (int mi = 0; mi < 4; ++mi)
#pragma unroll
      for (int ni = 0; ni < 4; ++ni) acc[mi][ni] = MFMA16(af[mi], bf[ni], acc[mi][ni]);
  }

  if (mat == 2) {  // V: transposed per-head store
#pragma unroll
    for (int mi = 0; mi < 4; ++mi) {
      const int row = m0 + wr * 64 + mi * 16 + lg * 4;  // (b, j)
      const int bb = row >> 10, jj = row & 1023;
#pragma unroll
      for (int ni = 0; ni < 4; ++ni) {
        const int col = n0 + wc * 64 + ni * 16 + li;  // (h, x)
        const int h = col >> 6, x = col & 63;
        short4v st;
#pragma unroll
        for (int r = 0; r < 4; ++r) st[r] = (short)f2bf(acc[mi][ni][r]);
        *(short4v*)(vtb + ((size_t)((bb * HH + h) * HD + x)) * NN + jj) = st;
      }
    }
  } else {
    u16* C = (mat == 0) ? kb : qb;
    const float scale = (mat == 0) ? SCLOG2 : 1.0f;
#pragma unroll
    for (int mi = 0; mi < 4; ++mi)
#pragma unroll
      for (int ni = 0; ni < 4; ++ni) {
        const int col = n0 + wc * 64 + ni * 16 + li;
        const int rowb = m0 + wr * 64 + mi * 16 + lg * 4;
#pragma unroll
        for (int r = 0; r < 4; ++r)
          C[(size_t)(rowb + r) * 1024 + col] = f2bf(acc[mi][ni][r] * scale);
      }
  }
}

// ---------------- output GEMM: out = attb @ Wo^T + bo, mask-zeroed ----------
__global__ __launch_bounds__(256) void gemm_out(const u16* __restrict__ A, const u16* __restrict__ Bw,
                                                float* __restrict__ C, const float* __restrict__ bias,
                                                const int* __restrict__ lens) {
  constexpr int K = 1024;
  __shared__ u16 As[128 * 32];
  __shared__ u16 Bs[128 * 32];
  const int m0 = blockIdx.x * 128;
  const int n0 = blockIdx.y * 128;
  const int t = threadIdx.x;
  const int lane = t & 63;
  const int w = t >> 6;
  const int wr = w >> 1, wc = w & 1;
  const int li = lane & 15, lg = lane >> 4;
  f32x4 acc[4][4] = {};
  const int off0 = t * 16, off1 = (256 + t) * 16;
  const int r0 = off0 >> 6, kb0 = (off0 & 63) >> 1;
  const int r1 = off1 >> 6, kb1 = (off1 & 63) >> 1;

  for (int k0 = 0; k0 < K; k0 += 32) {
    __syncthreads();
    gld16(A + (size_t)(m0 + r0) * K + k0 + kb0, As + off0 / 2);
    gld16(A + (size_t)(m0 + r1) * K + k0 + kb1, As + off1 / 2);
    gld16(Bw + (size_t)(n0 + r0) * K + k0 + kb0, Bs + off0 / 2);
    gld16(Bw + (size_t)(n0 + r1) * K + k0 + kb1, Bs + off1 / 2);
    __syncthreads();
    short8 af[4], bf[4];
#pragma unroll
    for (int mi = 0; mi < 4; ++mi)
      af[mi] = *(const short8*)(As + (wr * 64 + mi * 16 + li) * 32 + lg * 8);
#pragma unroll
    for (int ni = 0; ni < 4; ++ni)
      bf[ni] = *(const short8*)(Bs + (wc * 64 + ni * 16 + li) * 32 + lg * 8);
#pragma unroll
    for (int mi = 0; mi < 4; ++mi)
#pragma unroll
      for (int ni = 0; ni < 4; ++ni) acc[mi][ni] = MFMA16(af[mi], bf[ni], acc[mi][ni]);
  }

#pragma unroll
  for (int ni = 0; ni < 4; ++ni) {
    const int col = n0 + wc * 64 + ni * 16 + li;
    const float bv = bias[col];
#pragma unroll
    for (int mi = 0; mi < 4; ++mi) {
      const int rowb = m0 + wr * 64 + mi * 16 + lg * 4;
#pragma unroll
      for (int r = 0; r < 4; ++r) {
        const int row = rowb + r;
        const int bb = row >> 10, ii = row & 1023;
        const float v = (ii < lens[bb]) ? (acc[mi][ni][r] + bv) : 0.f;
        C[(size_t)row * 1024 + col] = v;
      }
    }
  }
}

// ---------------- flash attention, 4 waves/block, 32 i-rows/wave ------------
// 1D grid of 1024 blocks, XCD-swizzled (T1) so the 8 i-chunk blocks sharing
// one (b,h)'s Q/V panels land on the SAME XCD: work = (bid&7)*128 + bid>>3
// (hardware round-robins consecutive bids across the 8 XCDs). Per-XCD working
// set: 16 groups x (Q 128K + V 128K + K 16K) ~ 4.3 MB ~ L2.
// S^T = mfma32(A=Q-frag, B=K-frag): lane l holds col i = l&31,
// row j = (reg&3) + 8*(reg>>2) + 4*(l>>5). Scores in exp2 domain (K
// pre-scaled by 0.125*log2e). Q/V tiles (64 j) double-buffered in LDS in
// FRAGMENT-MAJOR order (linear global_load_lds dest, conflict-free b128 reads).
__global__ __launch_bounds__(256) void attn_kernel(const u16* __restrict__ Kb, const u16* __restrict__ Qb,
                                                   const u16* __restrict__ Vtb, u16* __restrict__ attb,
                                                   const int* __restrict__ lens) {
  const int bid = blockIdx.x;
  const int work = (bid & 7) * 128 + (bid >> 3);  // bijective, 1024 = 8*128
  const int ic = work & 7, h = (work >> 3) & 15, b = work >> 7;
  const int len = lens[b];
  const int i0 = ic * 128;
  if (i0 >= len) return;  // fully-masked rows zeroed by final GEMM
  const int t = threadIdx.x;
  const int w = t >> 6, l = t & 63;
  const int l31 = l & 31, hi = l >> 5;
  const int i0w = i0 + w * 32;

  __shared__ u16 Qs[2][4096];  // 8KB per buffer
  __shared__ u16 Vs[2][4096];

  // K fragments (B operand): col i = l31, k(hd) = ks*16 + hi*8 + e
  short8 kf[4];
  {
    const u16* kp = Kb + ((size_t)(b * NN + i0w + l31)) * DD + h * HD + hi * 8;
#pragma unroll
    for (int ks = 0; ks < 4; ++ks) kf[ks] = *(const short8*)(kp + ks * 16);
  }

  const size_t qsrc = ((size_t)(b * NN) + l31) * DD + h * HD + w * 16 + hi * 8;
  const size_t vsrc = ((size_t)((b * HH + h) * HD + l31)) * NN + w * 16 + hi * 8;

  auto STAGE = [&](int buf, int j0) {
    u16* qd = &Qs[buf][0] + t * 8;
    u16* vd = &Vs[buf][0] + t * 8;
    gld16(Qb + qsrc + (size_t)j0 * DD, qd);
    gld16(Qb + qsrc + (size_t)(j0 + 32) * DD, qd + 2048);
    gld16(Vtb + vsrc + j0, vd);
    gld16(Vtb + vsrc + 32 * NN + j0, vd + 2048);
  };

  f32x16 o0 = zero16(), o1 = zero16();
  float m_run = -3.0e38f, l_run = 0.f;
  const int nt = (len + 63) >> 6;

  STAGE(0, 0);
  __syncthreads();
  for (int jt = 0; jt < nt; ++jt) {
    const int cur = jt & 1;
    const int j0 = jt * 64;
    if (jt + 1 < nt) STAGE(cur ^ 1, j0 + 64);  // async prefetch, drained at end barrier

    const u16* Qc = &Qs[cur][0];
    const u16* Vc = &Vs[cur][0];
    f32x16 s0 = zero16(), s1 = zero16();
    __builtin_amdgcn_s_setprio(1);
#pragma unroll
    for (int ks = 0; ks < 4; ++ks) {
      const short8 qf = *(const short8*)(Qc + (ks * 64 + l) * 8);
      s0 = MFMA32(qf, kf[ks], s0);
    }
#pragma unroll
    for (int ks = 0; ks < 4; ++ks) {
      const short8 qf = *(const short8*)(Qc + ((4 + ks) * 64 + l) * 8);
      s1 = MFMA32(qf, kf[ks], s1);
    }
    __builtin_amdgcn_s_setprio(0);

    if (j0 + 64 > len) {  // uniform; only possible on last tile
#pragma unroll
      for (int r = 0; r < 16; ++r) {
        const int jl = (r & 3) + 8 * (r >> 2) + 4 * hi;
        if (j0 + jl >= len) s0[r] = -3.0e38f;
        if (j0 + 32 + jl >= len) s1[r] = -3.0e38f;
      }
    }

    float pmax = s0[0];
#pragma unroll
    for (int r = 1; r < 16; ++r) pmax = fmaxf(pmax, s0[r]);
#pragma unroll
    for (int r = 0; r < 16; ++r) pmax = fmaxf(pmax, s1[r]);
    pmax = fmaxf(pmax, __shfl_xor(pmax, 32));

    // defer-max (T13): skip O-rescale while tile max within 11.5 (log2) of m_run
    if (!__all(pmax <= m_run + 11.5f)) {
      const float mnew = fmaxf(m_run, pmax);
      const float al = __builtin_amdgcn_exp2f(m_run - mnew);
      l_run *= al;
#pragma unroll
      for (int r = 0; r < 16; ++r) { o0[r] *= al; o1[r] *= al; }
      m_run = mnew;
    }

    float rs = 0.f;
#pragma unroll
    for (int r = 0; r < 16; ++r) { const float p = __builtin_amdgcn_exp2f(s0[r] - m_run); s0[r] = p; rs += p; }
#pragma unroll
    for (int r = 0; r < 16; ++r) { const float p = __builtin_amdgcn_exp2f(s1[r] - m_run); s1[r] = p; rs += p; }
    rs += __shfl_xor(rs, 32);
    l_run += rs;

    // P -> PV B-fragments: per 16-j chunk, 4 cvt_pk + 2 permlane32_swap (T12).
    // v_permlane32_swap_b32 vdst, vsrc: vdst_new = {vdst.lo, vsrc.lo},
    // vsrc_new = {vdst.hi, vsrc.hi}; vdst = low-j word, vsrc = +8 word.
    short8 pf[4];
#pragma unroll
    for (int jk = 0; jk < 4; ++jk) {
      const f32x16& ss = (jk < 2) ? s0 : s1;
      const int kk = jk & 1;
      unsigned W0 = cvtpk(ss[8 * kk + 0], ss[8 * kk + 1]);
      unsigned W1 = cvtpk(ss[8 * kk + 2], ss[8 * kk + 3]);
      unsigned W2 = cvtpk(ss[8 * kk + 4], ss[8 * kk + 5]);
      unsigned W3 = cvtpk(ss[8 * kk + 6], ss[8 * kk + 7]);
      asm("v_permlane32_swap_b32 %0, %1" : "+v"(W0), "+v"(W2));
      asm("v_permlane32_swap_b32 %0, %1" : "+v"(W1), "+v"(W3));
      union { unsigned u[4]; short8 s; } pu;
      pu.u[0] = W0; pu.u[1] = W1; pu.u[2] = W2; pu.u[3] = W3;
      pf[jk] = pu.s;
    }

    __builtin_amdgcn_s_setprio(1);
#pragma unroll
    for (int kkg = 0; kkg < 4; ++kkg) {
      const short8 vf = *(const short8*)(Vc + (kkg * 64 + l) * 8);
      o0 = MFMA32(vf, pf[kkg], o0);
    }
#pragma unroll
    for (int kkg = 0; kkg < 4; ++kkg) {
      const short8 vf = *(const short8*)(Vc + ((4 + kkg) * 64 + l) * 8);
      o1 = MFMA32(vf, pf[kkg], o1);
    }
    __builtin_amdgcn_s_setprio(0);
    __syncthreads();  // drains prefetch (vmcnt) + this tile's ds_reads (lgkm)
  }

  const float inv = 1.f / l_run;
  u16* op = attb + (size_t)(b * NN + i0w + l31) * DD + h * HD + hi * 4;
#pragma unroll
  for (int xs = 0; xs < 2; ++xs) {
    const f32x16& oo = xs ? o1 : o0;
#pragma unroll
    for (int q = 0; q < 4; ++q) {
      short4v st;
#pragma unroll
      for (int e = 0; e < 4; ++e) st[e] = (short)f2bf(oo[q * 4 + e] * inv);
      *(short4v*)(op + xs * 32 + q * 8) = st;
    }
  }
}

// ---------------------------------------------------------------------------
extern "C" void kernel_launch(void* const* d_in, const int* in_sizes, int n_in,
                              void* d_out, int out_size, void* d_ws, size_t ws_size,
                              hipStream_t stream) {
  const float* x = (const float*)d_in[0];
  const unsigned char* mask = (const unsigned char*)d_in[1];
  const float* Wk = (const float*)d_in[2];
  const float* Wq = (const float*)d_in[3];
  const float* Wv = (const float*)d_in[4];
  const float* Wo = (const float*)d_in[5];
  const float* bo = (const float*)d_in[6];
  float* out = (float*)d_out;

  char* ws = (char*)d_ws;
  size_t o = 0;
  int* lens = (int*)(ws + o); o += 256;
  u16* xb  = (u16*)(ws + o); o += (size_t)MM * DD * 2;
  u16* wkb = (u16*)(ws + o); o += (size_t)DD * DD * 2;
  u16* wqb = (u16*)(ws + o); o += (size_t)DD * DD * 2;
  u16* wvb = (u16*)(ws + o); o += (size_t)DD * DD * 2;
  u16* wob = (u16*)(ws + o); o += (size_t)DD * DD * 2;
  u16* kb  = (u16*)(ws + o); o += (size_t)MM * DD * 2;
  u16* qb  = (u16*)(ws + o); o += (size_t)MM * DD * 2;
  u16* vtb = (u16*)(ws + o); o += (size_t)MM * DD * 2;
  u16* attb = xb;  // alias: x only needed until projections finish

  lens_kernel<<<dim3(1), dim3(256), 0, stream>>>(mask, lens);

  const int xn8 = MM * DD / 8;
  cast_bf16_kernel<<<dim3(xn8 / 256), dim3(256), 0, stream>>>(x, xb, xn8);
  cast4_bf16_kernel<<<dim3(DD * DD / 8 / 256, 4), dim3(256), 0, stream>>>(
      Wk, Wq, Wv, Wo, wkb, wqb, wvb, wob);

  gemm_qkv<<<dim3(MM / 128, 24), dim3(256), 0, stream>>>(xb, wkb, wqb, wvb, kb, qb, vtb);

  attn_kernel<<<dim3(1024), dim3(256), 0, stream>>>(kb, qb, vtb, attb, lens);

  gemm_out<<<dim3(MM / 128, DD / 128), dim3(256), 0, stream>>>(attb, wob, out, bo, lens);
}